// Round 3
// baseline (1411.762 us; speedup 1.0000x reference)
//
#include <hip/hip_runtime.h>

#define N_NODES 100000
#define N_EDGES 1600000
#define D 128
#define NB 1563            // ceil(N_NODES / 64) buckets of 64 rows
#define ACC_STRIDE 132

typedef short bf16x8 __attribute__((ext_vector_type(8)));
typedef float f32x4 __attribute__((ext_vector_type(4)));

__device__ __forceinline__ unsigned short f2bf(float x){
  union { float f; unsigned u; } v; v.f = x;
  unsigned r = v.u + 0x7fffu + ((v.u >> 16) & 1u);
  return (unsigned short)(r >> 16);
}

// global bucket histogram, LDS-staged
__global__ __launch_bounds__(256) void bhist_kernel(const int* __restrict__ rows,
                                                    int* __restrict__ bhist){
  __shared__ int lh[NB];
  for (int i = threadIdx.x; i < NB; i += 256) lh[i] = 0;
  __syncthreads();
  int base = blockIdx.x * 6250;      // 256 blocks x 6250 = 1.6M
  for (int i = threadIdx.x; i < 6250; i += 256)
    atomicAdd(&lh[rows[base + i] >> 6], 1);
  __syncthreads();
  for (int i = threadIdx.x; i < NB; i += 256){
    int c = lh[i];
    if (c) atomicAdd(&bhist[i], c);
  }
}

// exclusive scan of 1563 bucket counts -> bstart[0..NB] (sentinel), cursor
__global__ __launch_bounds__(1024) void bscan_kernel(const int* __restrict__ bhist,
                                                     int* __restrict__ bstart,
                                                     int* __restrict__ cursor){
  __shared__ int s[2048];
  __shared__ int ps[1024];
  int t = threadIdx.x;
  s[t]        = (t < NB)        ? bhist[t]        : 0;
  s[t + 1024] = (t + 1024 < NB) ? bhist[t + 1024] : 0;
  __syncthreads();
  ps[t] = s[2*t] + s[2*t + 1];
  __syncthreads();
  for (int off = 1; off < 1024; off <<= 1){
    int x = (t >= off) ? ps[t - off] : 0;
    __syncthreads();
    ps[t] += x;
    __syncthreads();
  }
  int excl = (t > 0) ? ps[t - 1] : 0;   // inclusive scan of pairs -> exclusive base
  int i0 = 2*t, i1 = 2*t + 1;
  if (i0 <= NB){ bstart[i0] = excl; if (i0 < NB) cursor[i0] = excl; }
  int e1 = excl + s[i0];
  if (i1 <= NB){ bstart[i1] = e1;   if (i1 < NB) cursor[i1] = e1; }
}

// bucket-cluster the edges: per-block hist -> one reservation per bucket -> place.
// packed edge: word0 = col | (local_row << 17), word1 = val bits
__global__ __launch_bounds__(256) void passA_kernel(const int* __restrict__ rows,
                                                    const int* __restrict__ cols,
                                                    const float* __restrict__ vals,
                                                    int* __restrict__ cursor,
                                                    int2* __restrict__ edges_s){
  __shared__ int lh[NB];
  __shared__ int lbase[NB];
  int t = threadIdx.x;
  for (int i = t; i < NB; i += 256) lh[i] = 0;
  __syncthreads();
  int base = blockIdx.x * 12500;     // 128 blocks x 12500 = 1.6M
  for (int i = t; i < 12500; i += 256)
    atomicAdd(&lh[rows[base + i] >> 6], 1);
  __syncthreads();
  for (int i = t; i < NB; i += 256){
    int c = lh[i];
    lbase[i] = c ? atomicAdd(&cursor[i], c) : 0;
    lh[i] = 0;                       // reuse as local placement cursor
  }
  __syncthreads();
  for (int i = t; i < 12500; i += 256){
    int r = rows[base + i];
    int b = r >> 6;
    int idx = atomicAdd(&lh[b], 1);
    edges_s[lbase[b] + idx] =
        make_int2(cols[base + i] | ((r & 63) << 17), __float_as_int(vals[base + i]));
  }
}

// WT[c][k] = bf16(W[k][c]) so B-fragments read contiguous k-runs
__global__ void transpose_w(const float* __restrict__ W, unsigned short* __restrict__ WT){
  int idx = blockIdx.x*256 + threadIdx.x;    // 0..16383
  int k = idx >> 7, c = idx & 127;
  WT[c*128 + k] = f2bf(W[idx]);
}

// one block per bucket: LDS fp32 accumulation of 64 rows x 128 dims.
// half-wave per edge; dims strided by 32 -> ds_add hits all 32 banks.
__global__ __launch_bounds__(256) void passB_kernel(const float* __restrict__ input,
                                                    const int* __restrict__ bstart,
                                                    const int2* __restrict__ edges,
                                                    ushort4* __restrict__ aggb){
  __shared__ float acc[64 * ACC_STRIDE];
  int t = threadIdx.x;
  for (int i = t; i < 64 * ACC_STRIDE; i += 256) acc[i] = 0.f;
  __syncthreads();

  int b = blockIdx.x;
  int start = bstart[b], end = bstart[b + 1];
  int m = end - start;
  int w = t >> 6, l = t & 63;
  int h = l >> 5, l32 = l & 31;
  int per = (m + 3) >> 2;
  int ws = start + w * per;
  int we = min(ws + per, end);
  int e = ws;

  for (; e + 4 <= we; e += 4){
    int2 mA = edges[e + h];
    int2 mB = edges[e + 2 + h];
    int cA = mA.x & 0x1FFFF; int rA = ((unsigned)mA.x) >> 17;
    int cB = mB.x & 0x1FFFF; int rB = ((unsigned)mB.x) >> 17;
    float vA = __int_as_float(mA.y), vB = __int_as_float(mB.y);
    const float* pA = input + (size_t)cA * 128 + l32;
    const float* pB = input + (size_t)cB * 128 + l32;
    float a0 = pA[0], a1 = pA[32], a2 = pA[64], a3 = pA[96];
    float b0 = pB[0], b1 = pB[32], b2 = pB[64], b3 = pB[96];
    atomicAdd(&acc[rA*ACC_STRIDE + l32      ], vA * a0);
    atomicAdd(&acc[rA*ACC_STRIDE + l32 + 32 ], vA * a1);
    atomicAdd(&acc[rA*ACC_STRIDE + l32 + 64 ], vA * a2);
    atomicAdd(&acc[rA*ACC_STRIDE + l32 + 96 ], vA * a3);
    atomicAdd(&acc[rB*ACC_STRIDE + l32      ], vB * b0);
    atomicAdd(&acc[rB*ACC_STRIDE + l32 + 32 ], vB * b1);
    atomicAdd(&acc[rB*ACC_STRIDE + l32 + 64 ], vB * b2);
    atomicAdd(&acc[rB*ACC_STRIDE + l32 + 96 ], vB * b3);
  }
  for (; e + 2 <= we; e += 2){
    int2 mA = edges[e + h];
    int cA = mA.x & 0x1FFFF; int rA = ((unsigned)mA.x) >> 17;
    float vA = __int_as_float(mA.y);
    const float* pA = input + (size_t)cA * 128 + l32;
    atomicAdd(&acc[rA*ACC_STRIDE + l32      ], vA * pA[0]);
    atomicAdd(&acc[rA*ACC_STRIDE + l32 + 32 ], vA * pA[32]);
    atomicAdd(&acc[rA*ACC_STRIDE + l32 + 64 ], vA * pA[64]);
    atomicAdd(&acc[rA*ACC_STRIDE + l32 + 96 ], vA * pA[96]);
  }
  if (e < we && h == 0){
    int2 mA = edges[e];
    int cA = mA.x & 0x1FFFF; int rA = ((unsigned)mA.x) >> 17;
    float vA = __int_as_float(mA.y);
    const float* pA = input + (size_t)cA * 128 + l32;
    atomicAdd(&acc[rA*ACC_STRIDE + l32      ], vA * pA[0]);
    atomicAdd(&acc[rA*ACC_STRIDE + l32 + 32 ], vA * pA[32]);
    atomicAdd(&acc[rA*ACC_STRIDE + l32 + 64 ], vA * pA[64]);
    atomicAdd(&acc[rA*ACC_STRIDE + l32 + 96 ], vA * pA[96]);
  }
  __syncthreads();

  int rowbase = b * 64;
  for (int i = t; i < 2048; i += 256){      // 64 rows x 32 ushort4
    int r = i >> 5, c4 = i & 31;
    int grow = rowbase + r;
    if (grow < N_NODES){
      const float* p = &acc[r*ACC_STRIDE + c4*4];
      ushort4 hh;
      hh.x = f2bf(p[0]); hh.y = f2bf(p[1]); hh.z = f2bf(p[2]); hh.w = f2bf(p[3]);
      aggb[(size_t)grow*32 + c4] = hh;
    }
  }
}

// out = normalize(BETA*input + (1-BETA)*(agg @ W)) + bias, bf16 MFMA GEMM
// block = 256 threads = 4 waves; 64 rows x 128 cols per block
__global__ __launch_bounds__(256) void final_kernel(const ushort4* __restrict__ aggb,
                                                    const float* __restrict__ input,
                                                    const unsigned short* __restrict__ WT,
                                                    const float* __restrict__ bias,
                                                    float* __restrict__ out){
  __shared__ unsigned short Ws[128*136];   // WT[c][k], stride 136
  __shared__ unsigned short As[64*136];    // agg rows bf16
  int t = threadIdx.x;
  int block_row = blockIdx.x * 64;

  const ushort4* WT4 = (const ushort4*)WT;   // 4096 ushort4
  #pragma unroll
  for (int i = 0; i < 16; ++i){
    int idx4 = i*256 + t;
    int c = idx4 >> 5, k4 = idx4 & 31;
    ushort4 w = WT4[idx4];
    *((ushort4*)&Ws[c*136 + k4*4]) = w;
  }
  #pragma unroll
  for (int i = 0; i < 8; ++i){
    int idx4 = i*256 + t;                   // 2048 ushort4 = 64 rows x 32
    int row = idx4 >> 5, k4 = idx4 & 31;
    int grow = block_row + row;
    ushort4 h = make_ushort4(0,0,0,0);
    if (grow < N_NODES) h = aggb[(size_t)grow*32 + k4];
    *((ushort4*)&As[row*136 + k4*4]) = h;
  }
  __syncthreads();

  int wave = t >> 6, lane = t & 63;
  int q = lane >> 4, n = lane & 15;

  // A-frag: lane holds A[m = lane&15][k = q*8 + j]
  bf16x8 afr[4];
  #pragma unroll
  for (int ks = 0; ks < 4; ++ks)
    afr[ks] = *((const bf16x8*)&As[(wave*16 + n)*136 + ks*32 + q*8]);

  f32x4 acc[8];
  #pragma unroll
  for (int ct = 0; ct < 8; ++ct) acc[ct] = (f32x4){0.f, 0.f, 0.f, 0.f};

  #pragma unroll
  for (int ct = 0; ct < 8; ++ct){
    #pragma unroll
    for (int ks = 0; ks < 4; ++ks){
      bf16x8 bfr = *((const bf16x8*)&Ws[(ct*16 + n)*136 + ks*32 + q*8]);
      acc[ct] = __builtin_amdgcn_mfma_f32_16x16x32_bf16(afr[ks], bfr, acc[ct], 0, 0, 0);
    }
  }

  // C/D: col = lane&15 (+ct*16), row = q*4 + reg (+wave*16)
  int base_row = block_row + wave*16 + q*4;
  float v[8][4];
  float s[4] = {0.f, 0.f, 0.f, 0.f};
  #pragma unroll
  for (int reg = 0; reg < 4; ++reg){
    int grow = base_row + reg;
    const float* inrow = input + (size_t)grow * D;
    #pragma unroll
    for (int ct = 0; ct < 8; ++ct){
      float inp = (grow < N_NODES) ? inrow[ct*16 + n] : 0.f;
      float val = fmaf(0.999f, acc[ct][reg], 0.001f * inp);
      v[ct][reg] = val;
      s[reg] = fmaf(val, val, s[reg]);
    }
  }
  #pragma unroll
  for (int reg = 0; reg < 4; ++reg){
    float x = s[reg];
    x += __shfl_xor(x, 1);
    x += __shfl_xor(x, 2);
    x += __shfl_xor(x, 4);
    x += __shfl_xor(x, 8);
    s[reg] = x;
  }
  #pragma unroll
  for (int reg = 0; reg < 4; ++reg){
    int grow = base_row + reg;
    if (grow >= N_NODES) continue;
    float scale = 1.f / fmaxf(sqrtf(s[reg]), 1e-12f);
    float* outrow = out + (size_t)grow * D;
    #pragma unroll
    for (int ct = 0; ct < 8; ++ct){
      outrow[ct*16 + n] = fmaf(v[ct][reg], scale, bias[ct*16 + n]);
    }
  }
}

extern "C" void kernel_launch(void* const* d_in, const int* in_sizes, int n_in,
                              void* d_out, int out_size, void* d_ws, size_t ws_size,
                              hipStream_t stream){
  const float* input  = (const float*)d_in[0];
  const int*   erows  = (const int*)d_in[1];
  const int*   ecols  = (const int*)d_in[2];
  const float* evals  = (const float*)d_in[3];
  const float* weight = (const float*)d_in[4];
  const float* bias   = (const float*)d_in[5];
  float* out = (float*)d_out;

  int*   bhist  = (int*)d_ws;                     // NB
  int*   bstart = bhist + NB;                     // NB+1
  int*   cursor = bstart + NB + 1;                // NB
  int2*  edges_s = (int2*)(cursor + NB);          // N_EDGES int2 (offset 18760 B, 8-aligned)
  ushort4* aggb = (ushort4*)(edges_s + N_EDGES);  // N_NODES*32 ushort4
  unsigned short* WTg = (unsigned short*)(aggb + (size_t)N_NODES * 32);  // 16384

  hipMemsetAsync(bhist, 0, NB * sizeof(int), stream);
  bhist_kernel<<<256, 256, 0, stream>>>(erows, bhist);
  bscan_kernel<<<1, 1024, 0, stream>>>(bhist, bstart, cursor);
  passA_kernel<<<128, 256, 0, stream>>>(erows, ecols, evals, cursor, edges_s);
  transpose_w<<<64, 256, 0, stream>>>(weight, WTg);
  passB_kernel<<<NB, 256, 0, stream>>>(input, bstart, edges_s, aggb);
  final_kernel<<<(N_NODES + 63)/64, 256, 0, stream>>>(aggb, input, WTg, bias, out);
}

// Round 4
// 350.991 us; speedup vs baseline: 4.0222x; 4.0222x over previous
//
#include <hip/hip_runtime.h>

#define N_NODES 100000
#define N_EDGES 1600000
#define D 128
#define NB 1563            // ceil(N_NODES / 64) buckets of 64 rows
#define STAGE 2048         // max edges per bucket staged in LDS (mean 1024, sd 32)

typedef short bf16x8 __attribute__((ext_vector_type(8)));
typedef float f32x4 __attribute__((ext_vector_type(4)));

__device__ __forceinline__ unsigned short f2bf(float x){
  union { float f; unsigned u; } v; v.f = x;
  unsigned r = v.u + 0x7fffu + ((v.u >> 16) & 1u);
  return (unsigned short)(r >> 16);
}

__device__ __forceinline__ float bf2f(unsigned short h){
  union { unsigned u; float f; } v; v.u = ((unsigned)h) << 16;
  return v.f;
}

// fp32 input -> bf16 copy (gather source for agg)
__global__ __launch_bounds__(256) void convert_input(const float4* __restrict__ in4,
                                                     ushort4* __restrict__ outb){
  int i = blockIdx.x*256 + threadIdx.x;        // 12500*256 = 3.2M = N*D/4
  float4 a = in4[i];
  ushort4 h;
  h.x = f2bf(a.x); h.y = f2bf(a.y); h.z = f2bf(a.z); h.w = f2bf(a.w);
  outb[i] = h;
}

// global bucket histogram, LDS-staged
__global__ __launch_bounds__(256) void bhist_kernel(const int* __restrict__ rows,
                                                    int* __restrict__ bhist){
  __shared__ int lh[NB];
  for (int i = threadIdx.x; i < NB; i += 256) lh[i] = 0;
  __syncthreads();
  int base = blockIdx.x * 6250;      // 256 blocks x 6250 = 1.6M
  for (int i = threadIdx.x; i < 6250; i += 256)
    atomicAdd(&lh[rows[base + i] >> 6], 1);
  __syncthreads();
  for (int i = threadIdx.x; i < NB; i += 256){
    int c = lh[i];
    if (c) atomicAdd(&bhist[i], c);
  }
}

// exclusive scan of 1563 bucket counts -> bstart[0..NB] (sentinel), cursor
__global__ __launch_bounds__(1024) void bscan_kernel(const int* __restrict__ bhist,
                                                     int* __restrict__ bstart,
                                                     int* __restrict__ cursor){
  __shared__ int s[2048];
  __shared__ int ps[1024];
  int t = threadIdx.x;
  s[t]        = (t < NB)        ? bhist[t]        : 0;
  s[t + 1024] = (t + 1024 < NB) ? bhist[t + 1024] : 0;
  __syncthreads();
  ps[t] = s[2*t] + s[2*t + 1];
  __syncthreads();
  for (int off = 1; off < 1024; off <<= 1){
    int x = (t >= off) ? ps[t - off] : 0;
    __syncthreads();
    ps[t] += x;
    __syncthreads();
  }
  int excl = (t > 0) ? ps[t - 1] : 0;
  int i0 = 2*t, i1 = 2*t + 1;
  if (i0 <= NB){ bstart[i0] = excl; if (i0 < NB) cursor[i0] = excl; }
  int e1 = excl + s[i0];
  if (i1 <= NB){ bstart[i1] = e1;   if (i1 < NB) cursor[i1] = e1; }
}

// bucket-cluster the edges: per-block hist -> one reservation per bucket -> place.
// packed edge: word0 = col | (local_row << 17), word1 = val bits
__global__ __launch_bounds__(256) void passA_kernel(const int* __restrict__ rows,
                                                    const int* __restrict__ cols,
                                                    const float* __restrict__ vals,
                                                    int* __restrict__ cursor,
                                                    int2* __restrict__ edges_s){
  __shared__ int lh[NB];
  __shared__ int lbase[NB];
  int t = threadIdx.x;
  for (int i = t; i < NB; i += 256) lh[i] = 0;
  __syncthreads();
  int base = blockIdx.x * 12500;     // 128 blocks x 12500 = 1.6M
  for (int i = t; i < 12500; i += 256)
    atomicAdd(&lh[rows[base + i] >> 6], 1);
  __syncthreads();
  for (int i = t; i < NB; i += 256){
    int c = lh[i];
    lbase[i] = c ? atomicAdd(&cursor[i], c) : 0;
    lh[i] = 0;                       // reuse as local placement cursor
  }
  __syncthreads();
  for (int i = t; i < 12500; i += 256){
    int r = rows[base + i];
    int b = r >> 6;
    int idx = atomicAdd(&lh[b], 1);
    edges_s[lbase[b] + idx] =
        make_int2(cols[base + i] | ((r & 63) << 17), __float_as_int(vals[base + i]));
  }
}

// within-bucket row sort (in place) + emit CSR row_start/counts.
// One block per bucket; bucket edges staged in LDS.
__global__ __launch_bounds__(256) void passB2_kernel(int2* __restrict__ edges,
                                                     const int* __restrict__ bstart,
                                                     int* __restrict__ row_start,
                                                     int* __restrict__ counts){
  __shared__ int2 st[STAGE];
  __shared__ int hist[64];
  __shared__ int cur[64];
  int t = threadIdx.x;
  int b = blockIdx.x;
  int start = bstart[b], end = bstart[b + 1];
  int m = end - start;
  if (t < 64) hist[t] = 0;
  __syncthreads();
  for (int i = t; i < m; i += 256){
    int2 e = edges[start + i];
    st[i] = e;
    atomicAdd(&hist[((unsigned)e.x) >> 17], 1);
  }
  __syncthreads();
  if (t < 64){
    int c = hist[t];
    int x = c;
    #pragma unroll
    for (int off = 1; off < 64; off <<= 1){
      int y = __shfl_up(x, off);
      if (t >= off) x += y;
    }
    int excl = x - c;
    cur[t] = excl;
    int grow = b*64 + t;
    row_start[grow] = start + excl;
    counts[grow] = c;
  }
  __syncthreads();
  for (int i = t; i < m; i += 256){
    int2 e = st[i];
    int r = ((unsigned)e.x) >> 17;
    int pos = atomicAdd(&cur[r], 1);
    edges[start + pos] = make_int2(e.x & 0x1FFFF, e.y);
  }
}

// WT[c][k] = bf16(W[k][c]) so B-fragments read contiguous k-runs
__global__ void transpose_w(const float* __restrict__ W, unsigned short* __restrict__ WT){
  int idx = blockIdx.x*256 + threadIdx.x;    // 0..16383
  int k = idx >> 7, c = idx & 127;
  WT[c*128 + k] = f2bf(W[idx]);
}

// 32-lane group per row, ushort4 (4 bf16 dims) per lane, unroll x4 for MLP.
__global__ __launch_bounds__(256) void agg_kernel(const ushort4* __restrict__ inb4,
                                                  const int* __restrict__ row_start,
                                                  const int* __restrict__ counts,
                                                  const int2* __restrict__ edges,
                                                  ushort4* __restrict__ aggb){
  int g = threadIdx.x >> 5, l = threadIdx.x & 31;
  int row = blockIdx.x*8 + g;                 // grid = 12500 blocks, exact
  int start = row_start[row];
  int n = counts[row];
  int e = start, end = start + n;

  float4 a0 = make_float4(0.f,0.f,0.f,0.f);
  float4 a1 = make_float4(0.f,0.f,0.f,0.f);
  float4 a2 = make_float4(0.f,0.f,0.f,0.f);
  float4 a3 = make_float4(0.f,0.f,0.f,0.f);

  for (; e + 4 <= end; e += 4){
    int2 e0 = edges[e+0];
    int2 e1 = edges[e+1];
    int2 e2 = edges[e+2];
    int2 e3 = edges[e+3];
    ushort4 x0 = inb4[(size_t)e0.x*32 + l];
    ushort4 x1 = inb4[(size_t)e1.x*32 + l];
    ushort4 x2 = inb4[(size_t)e2.x*32 + l];
    ushort4 x3 = inb4[(size_t)e3.x*32 + l];
    float v0 = __int_as_float(e0.y), v1 = __int_as_float(e1.y);
    float v2 = __int_as_float(e2.y), v3 = __int_as_float(e3.y);
    a0.x = fmaf(v0, bf2f(x0.x), a0.x); a0.y = fmaf(v0, bf2f(x0.y), a0.y);
    a0.z = fmaf(v0, bf2f(x0.z), a0.z); a0.w = fmaf(v0, bf2f(x0.w), a0.w);
    a1.x = fmaf(v1, bf2f(x1.x), a1.x); a1.y = fmaf(v1, bf2f(x1.y), a1.y);
    a1.z = fmaf(v1, bf2f(x1.z), a1.z); a1.w = fmaf(v1, bf2f(x1.w), a1.w);
    a2.x = fmaf(v2, bf2f(x2.x), a2.x); a2.y = fmaf(v2, bf2f(x2.y), a2.y);
    a2.z = fmaf(v2, bf2f(x2.z), a2.z); a2.w = fmaf(v2, bf2f(x2.w), a2.w);
    a3.x = fmaf(v3, bf2f(x3.x), a3.x); a3.y = fmaf(v3, bf2f(x3.y), a3.y);
    a3.z = fmaf(v3, bf2f(x3.z), a3.z); a3.w = fmaf(v3, bf2f(x3.w), a3.w);
  }
  for (; e < end; ++e){
    int2 ee = edges[e];
    ushort4 x = inb4[(size_t)ee.x*32 + l];
    float v = __int_as_float(ee.y);
    a0.x = fmaf(v, bf2f(x.x), a0.x); a0.y = fmaf(v, bf2f(x.y), a0.y);
    a0.z = fmaf(v, bf2f(x.z), a0.z); a0.w = fmaf(v, bf2f(x.w), a0.w);
  }
  float4 s;
  s.x = (a0.x + a1.x) + (a2.x + a3.x);
  s.y = (a0.y + a1.y) + (a2.y + a3.y);
  s.z = (a0.z + a1.z) + (a2.z + a3.z);
  s.w = (a0.w + a1.w) + (a2.w + a3.w);
  ushort4 h;
  h.x = f2bf(s.x); h.y = f2bf(s.y); h.z = f2bf(s.z); h.w = f2bf(s.w);
  aggb[(size_t)row*32 + l] = h;
}

// out = normalize(BETA*input + (1-BETA)*(agg @ W)) + bias, bf16 MFMA GEMM
// block = 256 threads = 4 waves; 64 rows x 128 cols per block
__global__ __launch_bounds__(256) void final_kernel(const ushort4* __restrict__ aggb,
                                                    const float* __restrict__ input,
                                                    const unsigned short* __restrict__ WT,
                                                    const float* __restrict__ bias,
                                                    float* __restrict__ out){
  __shared__ unsigned short Ws[128*136];   // WT[c][k], stride 136
  __shared__ unsigned short As[64*136];    // agg rows bf16
  int t = threadIdx.x;
  int block_row = blockIdx.x * 64;

  const ushort4* WT4 = (const ushort4*)WT;   // 4096 ushort4
  #pragma unroll
  for (int i = 0; i < 16; ++i){
    int idx4 = i*256 + t;
    int c = idx4 >> 5, k4 = idx4 & 31;
    ushort4 w = WT4[idx4];
    *((ushort4*)&Ws[c*136 + k4*4]) = w;
  }
  #pragma unroll
  for (int i = 0; i < 8; ++i){
    int idx4 = i*256 + t;                   // 2048 ushort4 = 64 rows x 32
    int row = idx4 >> 5, k4 = idx4 & 31;
    int grow = block_row + row;
    ushort4 h = make_ushort4(0,0,0,0);
    if (grow < N_NODES) h = aggb[(size_t)grow*32 + k4];
    *((ushort4*)&As[row*136 + k4*4]) = h;
  }
  __syncthreads();

  int wave = t >> 6, lane = t & 63;
  int q = lane >> 4, n = lane & 15;

  // A-frag: lane holds A[m = lane&15][k = q*8 + j]
  bf16x8 afr[4];
  #pragma unroll
  for (int ks = 0; ks < 4; ++ks)
    afr[ks] = *((const bf16x8*)&As[(wave*16 + n)*136 + ks*32 + q*8]);

  f32x4 acc[8];
  #pragma unroll
  for (int ct = 0; ct < 8; ++ct) acc[ct] = (f32x4){0.f, 0.f, 0.f, 0.f};

  #pragma unroll
  for (int ct = 0; ct < 8; ++ct){
    #pragma unroll
    for (int ks = 0; ks < 4; ++ks){
      bf16x8 bfr = *((const bf16x8*)&Ws[(ct*16 + n)*136 + ks*32 + q*8]);
      acc[ct] = __builtin_amdgcn_mfma_f32_16x16x32_bf16(afr[ks], bfr, acc[ct], 0, 0, 0);
    }
  }

  // C/D: col = lane&15 (+ct*16), row = q*4 + reg (+wave*16)
  int base_row = block_row + wave*16 + q*4;
  float v[8][4];
  float s[4] = {0.f, 0.f, 0.f, 0.f};
  #pragma unroll
  for (int reg = 0; reg < 4; ++reg){
    int grow = base_row + reg;
    const float* inrow = input + (size_t)grow * D;
    #pragma unroll
    for (int ct = 0; ct < 8; ++ct){
      float inp = (grow < N_NODES) ? inrow[ct*16 + n] : 0.f;
      float val = fmaf(0.999f, acc[ct][reg], 0.001f * inp);
      v[ct][reg] = val;
      s[reg] = fmaf(val, val, s[reg]);
    }
  }
  #pragma unroll
  for (int reg = 0; reg < 4; ++reg){
    float x = s[reg];
    x += __shfl_xor(x, 1);
    x += __shfl_xor(x, 2);
    x += __shfl_xor(x, 4);
    x += __shfl_xor(x, 8);
    s[reg] = x;
  }
  #pragma unroll
  for (int reg = 0; reg < 4; ++reg){
    int grow = base_row + reg;
    if (grow >= N_NODES) continue;
    float scale = 1.f / fmaxf(sqrtf(s[reg]), 1e-12f);
    float* outrow = out + (size_t)grow * D;
    #pragma unroll
    for (int ct = 0; ct < 8; ++ct){
      outrow[ct*16 + n] = fmaf(v[ct][reg], scale, bias[ct*16 + n]);
    }
  }
}

extern "C" void kernel_launch(void* const* d_in, const int* in_sizes, int n_in,
                              void* d_out, int out_size, void* d_ws, size_t ws_size,
                              hipStream_t stream){
  const float* input  = (const float*)d_in[0];
  const int*   erows  = (const int*)d_in[1];
  const int*   ecols  = (const int*)d_in[2];
  const float* evals  = (const float*)d_in[3];
  const float* weight = (const float*)d_in[4];
  const float* bias   = (const float*)d_in[5];
  float* out = (float*)d_out;

  int*   bhist     = (int*)d_ws;                    // NB
  int*   bstart    = bhist + NB;                    // NB+1
  int*   bcursor   = bstart + NB + 1;               // NB
  int*   row_start = bcursor + NB;                  // 100032 (NB*64)
  int*   counts    = row_start + NB*64;             // 100032
  int2*  edges_s   = (int2*)(counts + NB*64);       // N_EDGES int2 (8B aligned: offset even)
  ushort4* aggb    = (ushort4*)(edges_s + N_EDGES); // N_NODES*32 ushort4 (bf16 agg)
  ushort4* inb     = aggb + (size_t)N_NODES * 32;   // N_NODES*32 ushort4 (bf16 input)
  unsigned short* WTg = (unsigned short*)(inb + (size_t)N_NODES * 32);  // 16384

  hipMemsetAsync(bhist, 0, NB * sizeof(int), stream);
  convert_input<<<12500, 256, 0, stream>>>((const float4*)input, inb);
  bhist_kernel<<<256, 256, 0, stream>>>(erows, bhist);
  bscan_kernel<<<1, 1024, 0, stream>>>(bhist, bstart, bcursor);
  passA_kernel<<<128, 256, 0, stream>>>(erows, ecols, evals, bcursor, edges_s);
  passB2_kernel<<<NB, 256, 0, stream>>>(edges_s, bstart, row_start, counts);
  transpose_w<<<64, 256, 0, stream>>>(weight, WTg);
  agg_kernel<<<N_NODES/8, 256, 0, stream>>>(inb, row_start, counts, edges_s, aggb);
  final_kernel<<<(N_NODES + 63)/64, 256, 0, stream>>>(aggb, input, WTg, bias, out);
}